// Round 2
// baseline (6380.605 us; speedup 1.0000x reference)
//
#include <hip/hip_runtime.h>
#include <hip/hip_bf16.h>

// ---------------------------------------------------------------------------
// SHINE forward, fp32 direct-conv. Workspace (218,841,088 B total):
//   concat : bf16 [2][576][256][256]  150,994,944 B   (9 slices of 64ch)
//   A, B   : f32  [2][64][256][256]   2 x 33,554,432 B  (ping-pong, reused at
//                                      all scales; residual adds are in-place)
//   w1t    : f32  [576][288]              663,552 B
//   w2t    : f32  [288][64]                73,728 B
// ---------------------------------------------------------------------------

#define HPX 65536   // 256*256
#define FCH 64

__device__ __forceinline__ float gelu_f(float x) {
  return 0.5f * x * (1.0f + erff(x * 0.70710678118654752440f));
}

// ---------------- conv0: base = concat(gelu(1x1(target)), gelu(3x3(feats)))
__global__ __launch_bounds__(256) void conv0_kernel(
    const float* __restrict__ img,   // [2][5][256][256]
    const float* __restrict__ w0a,   // [16][4][3][3]
    const float* __restrict__ w0b,   // [48]
    float* __restrict__ base)        // [2][64][256][256]
{
  long t = (long)blockIdx.x * 256 + threadIdx.x;   // over 2*64*65536
  int px = (int)(t & (HPX - 1));
  int c  = (int)((t >> 16) & 63);
  int n  = (int)(t >> 22);
  const float* im = img + (long)n * 5 * HPX;
  float r;
  if (c < 48) {
    r = w0b[c] * im[2 * HPX + px];
  } else {
    int co = c - 48;
    int y = px >> 8, x = px & 255;
    r = 0.0f;
    const int map4[4] = {0, 1, 3, 4};
    #pragma unroll
    for (int fi = 0; fi < 4; fi++) {
      const float* imc = im + (long)map4[fi] * HPX;
      #pragma unroll
      for (int ky = 0; ky < 3; ky++) {
        int yy = y + ky - 1;
        #pragma unroll
        for (int kx = 0; kx < 3; kx++) {
          int xx = x + kx - 1;
          bool ok = ((unsigned)yy < 256u) && ((unsigned)xx < 256u);
          float v = ok ? imc[yy * 256 + xx] : 0.0f;
          r = fmaf(w0a[((co * 4 + fi) * 3 + ky) * 3 + kx], v, r);
        }
      }
    }
  }
  base[t] = gelu_f(r);
}

// ---------------- generic 64->64 direct conv (+gelu, opt residual, opt bf16 out)
// NTAPS: 9 = full 3x3, 8 = donut. thread: 4 px x 8 oc; block: 4 waves = 32 oc.
// RESID: out may alias resid (each (o,p) is read-then-written by one thread).
template <int NTAPS, bool RESID, bool OBF16>
__global__ __launch_bounds__(256) void conv64_kernel(
    const float* __restrict__ in,     // [2][64][Hs][Ws]
    const float* __restrict__ wgt,    // [64][64][NTAPS]
    const float* __restrict__ resid,  // [2][64][Hs][Ws] or null
    void* __restrict__ outv,
    int Hs, int logW, int dil, long out_n_stride /*elements*/)
{
  const int Ws   = 1 << logW;
  const int npx  = Hs << logW;
  const int lane = threadIdx.x & 63;
  const int wave = threadIdx.x >> 6;
  const int obase = blockIdx.y * 32 + wave * 8;
  const int n = blockIdx.z;
  const float* inn = in + (long)n * FCH * npx;

  const int p0 = blockIdx.x * 256 + lane;

  int   poff[NTAPS][4];
  float pmsk[NTAPS][4];
  #pragma unroll
  for (int t = 0; t < NTAPS; t++) {
    const int kk = (NTAPS == 9) ? t : (t < 4 ? t : t + 1);
    const int dy = kk / 3 - 1, dx = kk % 3 - 1;
    const int dyd = dy * dil, dxd = dx * dil;
    #pragma unroll
    for (int k = 0; k < 4; k++) {
      int p = p0 + 64 * k;
      int y = p >> logW, x = p & (Ws - 1);
      int yy = y + dyd, xx = x + dxd;
      bool ok = ((unsigned)yy < (unsigned)Hs) && ((unsigned)xx < (unsigned)Ws);
      poff[t][k] = ok ? ((yy << logW) + xx) : 0;
      pmsk[t][k] = ok ? 1.0f : 0.0f;
    }
  }

  float acc[8][4];
  #pragma unroll
  for (int j = 0; j < 8; j++)
    #pragma unroll
    for (int k = 0; k < 4; k++) acc[j][k] = 0.0f;

  for (int ci = 0; ci < FCH; ci++) {
    const float* inc = inn + (long)ci * npx;
    const float* wc  = wgt + ((long)obase * FCH + ci) * NTAPS;
    #pragma unroll
    for (int t = 0; t < NTAPS; t++) {
      float w[8];
      #pragma unroll
      for (int j = 0; j < 8; j++) w[j] = wc[(long)j * FCH * NTAPS + t];
      float v[4];
      #pragma unroll
      for (int k = 0; k < 4; k++) v[k] = inc[poff[t][k]] * pmsk[t][k];
      #pragma unroll
      for (int j = 0; j < 8; j++)
        #pragma unroll
        for (int k = 0; k < 4; k++)
          acc[j][k] = fmaf(w[j], v[k], acc[j][k]);
    }
  }

  #pragma unroll
  for (int j = 0; j < 8; j++) {
    const int o = obase + j;
    #pragma unroll
    for (int k = 0; k < 4; k++) {
      const int p = p0 + 64 * k;
      float r = acc[j][k];
      if (RESID) r += resid[(long)n * FCH * npx + (long)o * npx + p];
      r = gelu_f(r);
      long oidx = (long)n * out_n_stride + (long)o * npx + p;
      if (OBF16) ((__hip_bfloat16*)outv)[oidx] = __float2bfloat16(r);
      else       ((float*)outv)[oidx] = r;
    }
  }
}

// ---------------- 2x2 average pool
__global__ __launch_bounds__(256) void avgpool_kernel(
    const float* __restrict__ in, float* __restrict__ out, int logWo)
{
  const int lognpo = 2 * logWo;
  long t = (long)blockIdx.x * 256 + threadIdx.x;   // over 2*64*npo
  int p  = (int)(t & ((1 << lognpo) - 1));
  long nc = t >> lognpo;
  int y = p >> logWo, x = p & ((1 << logWo) - 1);
  int Wi = 2 << logWo;
  const float* ic = in + nc * ((long)4 << lognpo);
  int b = (2 * y) * Wi + 2 * x;
  float s = ic[b] + ic[b + 1] + ic[b + Wi] + ic[b + Wi + 1];
  out[t] = 0.25f * s;
}

// ---------------- bilinear upsample (Hs->256, clamped == jax renorm) fused
// with 1x1 conv64 + gelu -> bf16 slice of concat. Hs==256 degenerates to
// identity sampling (wy=wx=0, all taps equal).
__global__ __launch_bounds__(256) void ups_kernel(
    const float* __restrict__ in,        // [2][64][Hs][Hs]
    const float* __restrict__ w,         // [64][64]
    __hip_bfloat16* __restrict__ slice,  // concat + sidx*64*HPX, n-stride 576*HPX
    int Hs)
{
  const int lane = threadIdx.x & 63;
  const int wave = threadIdx.x >> 6;
  const int obase = blockIdx.y * 32 + wave * 8;
  const int n = blockIdx.z;
  const int p0 = blockIdx.x * 256 + lane;
  const float* inn = in + (long)n * FCH * Hs * Hs;

  int o00[4], o01[4], o10[4], o11[4];
  float fwx[4], fwy[4];
  const float s = (float)Hs * (1.0f / 256.0f);
  #pragma unroll
  for (int k = 0; k < 4; k++) {
    int p = p0 + 64 * k;
    int Y = p >> 8, X = p & 255;
    float fy = ((float)Y + 0.5f) * s - 0.5f;
    float fx = ((float)X + 0.5f) * s - 0.5f;
    int y0 = (int)floorf(fy), x0 = (int)floorf(fx);
    fwy[k] = fy - (float)y0; fwx[k] = fx - (float)x0;
    int y0c = min(max(y0, 0), Hs - 1), y1c = min(max(y0 + 1, 0), Hs - 1);
    int x0c = min(max(x0, 0), Hs - 1), x1c = min(max(x0 + 1, 0), Hs - 1);
    o00[k] = y0c * Hs + x0c; o01[k] = y0c * Hs + x1c;
    o10[k] = y1c * Hs + x0c; o11[k] = y1c * Hs + x1c;
  }

  float acc[8][4];
  #pragma unroll
  for (int j = 0; j < 8; j++)
    #pragma unroll
    for (int k = 0; k < 4; k++) acc[j][k] = 0.0f;

  for (int ci = 0; ci < FCH; ci++) {
    const float* inc = inn + (long)ci * Hs * Hs;
    float v[4];
    #pragma unroll
    for (int k = 0; k < 4; k++) {
      float v00 = inc[o00[k]], v01 = inc[o01[k]];
      float v10 = inc[o10[k]], v11 = inc[o11[k]];
      float a = v00 + fwx[k] * (v01 - v00);
      float b = v10 + fwx[k] * (v11 - v10);
      v[k] = a + fwy[k] * (b - a);
    }
    float wv[8];
    #pragma unroll
    for (int j = 0; j < 8; j++) wv[j] = w[(obase + j) * FCH + ci];
    #pragma unroll
    for (int j = 0; j < 8; j++)
      #pragma unroll
      for (int k = 0; k < 4; k++)
        acc[j][k] = fmaf(wv[j], v[k], acc[j][k]);
  }

  #pragma unroll
  for (int j = 0; j < 8; j++)
    #pragma unroll
    for (int k = 0; k < 4; k++)
      slice[(long)n * 576 * HPX + (long)(obase + j) * HPX + p0 + 64 * k] =
          __float2bfloat16(gelu_f(acc[j][k]));
}

// ---------------- tiny transpose: w[R][C] -> wt[C][R]
__global__ __launch_bounds__(256) void transpose_w_kernel(
    const float* __restrict__ w, float* __restrict__ wt, int R, int C)
{
  int t = blockIdx.x * 256 + threadIdx.x;
  if (t < R * C) {
    int r = t / C, c = t % C;
    wt[c * R + r] = w[t];
  }
}

// ---------------- fused head: out = W3 @ gelu(W2 @ gelu(W1 @ concat))
// block = 256 thr, 64 px. phase1: wave w computes h[w*72 .. +72][64px] -> LDS.
// phase2: 4 lanes/px cover 64 mid-channels in chunks of 16, shuffle-reduce.
__global__ __launch_bounds__(256) void head_kernel(
    const __hip_bfloat16* __restrict__ v,  // [2][576][65536]
    const float* __restrict__ w1t,         // [576][288]
    const float* __restrict__ w2t,         // [288][64]
    const float* __restrict__ w3,          // [64]
    float* __restrict__ out)               // [2][65536]
{
  __shared__ float h[288][64];   // 73,728 B
  const int lane = threadIdx.x & 63;
  const int wave = threadIdx.x >> 6;
  const int n = blockIdx.y;
  const int pxb = blockIdx.x * 64;
  const __hip_bfloat16* vn = v + (long)n * 576 * HPX + pxb;

  { // phase 1
    const int ocb = wave * 72;
    float acc[72];
    #pragma unroll
    for (int j = 0; j < 72; j++) acc[j] = 0.0f;
    for (int ci = 0; ci < 576; ci++) {
      float x = __bfloat162float(vn[(long)ci * HPX + lane]);
      const float4* wr = (const float4*)(w1t + (long)ci * 288 + ocb);
      #pragma unroll
      for (int j4 = 0; j4 < 18; j4++) {
        float4 wv = wr[j4];
        acc[4 * j4 + 0] = fmaf(wv.x, x, acc[4 * j4 + 0]);
        acc[4 * j4 + 1] = fmaf(wv.y, x, acc[4 * j4 + 1]);
        acc[4 * j4 + 2] = fmaf(wv.z, x, acc[4 * j4 + 2]);
        acc[4 * j4 + 3] = fmaf(wv.w, x, acc[4 * j4 + 3]);
      }
    }
    #pragma unroll
    for (int j = 0; j < 72; j++) h[ocb + j][lane] = gelu_f(acc[j]);
  }
  __syncthreads();
  { // phase 2
    const int px = wave * 16 + (lane & 15);
    const int q  = lane >> 4;          // 0..3
    const int ob = q * 16;
    float acc2[16];
    #pragma unroll
    for (int j = 0; j < 16; j++) acc2[j] = 0.0f;
    for (int c = 0; c < 288; c++) {
      float hv = h[c][px];
      const float4* wr = (const float4*)(w2t + c * 64 + ob);
      #pragma unroll
      for (int j4 = 0; j4 < 4; j4++) {
        float4 wv = wr[j4];
        acc2[4 * j4 + 0] = fmaf(wv.x, hv, acc2[4 * j4 + 0]);
        acc2[4 * j4 + 1] = fmaf(wv.y, hv, acc2[4 * j4 + 1]);
        acc2[4 * j4 + 2] = fmaf(wv.z, hv, acc2[4 * j4 + 2]);
        acc2[4 * j4 + 3] = fmaf(wv.w, hv, acc2[4 * j4 + 3]);
      }
    }
    float r = 0.0f;
    #pragma unroll
    for (int j = 0; j < 16; j++) r = fmaf(w3[ob + j], gelu_f(acc2[j]), r);
    r += __shfl_xor(r, 16);
    r += __shfl_xor(r, 32);
    if (q == 0) out[(long)n * HPX + pxb + px] = r;
  }
}

// ---------------------------------------------------------------------------
// host-side helpers
// ---------------------------------------------------------------------------
static inline void conv9(const float* in, const float* w, float* out,
                         int Hs, int logW, hipStream_t s) {
  int npx = Hs << logW;
  conv64_kernel<9, false, false><<<dim3(npx / 256, 2, 2), 256, 0, s>>>(
      in, w, nullptr, out, Hs, logW, 1, (long)FCH * npx);
}
// second conv of a resblock, residual add; out aliases resid (in-place safe)
static inline void conv9r(const float* in, const float* w, float* resid_out,
                          int Hs, int logW, hipStream_t s) {
  int npx = Hs << logW;
  conv64_kernel<9, true, false><<<dim3(npx / 256, 2, 2), 256, 0, s>>>(
      in, w, resid_out, resid_out, Hs, logW, 1, (long)FCH * npx);
}
static inline void donut_f(const float* in, const float* w, float* out,
                           int Hs, int logW, int dil, hipStream_t s) {
  int npx = Hs << logW;
  conv64_kernel<8, false, false><<<dim3(npx / 256, 2, 2), 256, 0, s>>>(
      in, w, nullptr, out, Hs, logW, dil, (long)FCH * npx);
}
static inline void donut_b(const float* in, const float* w, __hip_bfloat16* slice,
                           int dil, hipStream_t s) {
  conv64_kernel<8, false, true><<<dim3(256, 2, 2), 256, 0, s>>>(
      in, w, nullptr, slice, 256, 8, dil, (long)576 * HPX);
}
static inline void ups(const float* in, const float* w, __hip_bfloat16* slice,
                       int Hs, hipStream_t s) {
  ups_kernel<<<dim3(256, 2, 2), 256, 0, s>>>(in, w, slice, Hs);
}
static inline void avgpool(const float* in, float* out, int logWo, hipStream_t s) {
  long total = (long)2 * FCH * (1L << (2 * logWo));
  avgpool_kernel<<<(int)(total / 256), 256, 0, s>>>(in, out, logWo);
}

extern "C" void kernel_launch(void* const* d_in, const int* in_sizes, int n_in,
                              void* d_out, int out_size, void* d_ws, size_t ws_size,
                              hipStream_t stream) {
  const float* img      = (const float*)d_in[0];
  const float* w0a      = (const float*)d_in[1];
  const float* w0b      = (const float*)d_in[2];
  const float* first_p  = (const float*)d_in[3];
  const float* cl10     = (const float*)d_in[4];   // [4][2][64*64*9]
  const float* cl2      = (const float*)d_in[5];
  const float* dil_p    = (const float*)d_in[6];   // [4][64*64*8]
  const float* dilres_p = (const float*)d_in[7];
  const float* ups_w    = (const float*)d_in[8];   // [4][64*64]
  const float* w1       = (const float*)d_in[9];   // [288][576]
  const float* w2       = (const float*)d_in[10];  // [64][288]
  const float* w3       = (const float*)d_in[11];  // [64]

  const size_t CONCAT_B = 150994944ul;             // 2*576*65536*2
  const size_t PBUF_B   = 33554432ul;              // 2*64*65536*4
  const size_t W1T_B    = 576ul * 288 * 4;
  const size_t W2T_B    = 288ul * 64 * 4;
  const size_t NEED = CONCAT_B + 2 * PBUF_B + W1T_B + W2T_B;  // 218,841,088

  if (ws_size < NEED) {
    // diagnostic fallback: clean absmax failure instead of a page fault
    hipMemsetAsync(d_out, 0, (size_t)out_size * 4, stream);
    return;
  }

  char* wsb = (char*)d_ws;
  __hip_bfloat16* concat = (__hip_bfloat16*)wsb;
  float* A   = (float*)(wsb + CONCAT_B);
  float* B   = (float*)(wsb + CONCAT_B + PBUF_B);
  float* w1t = (float*)(wsb + CONCAT_B + 2 * PBUF_B);
  float* w2t = (float*)(wsb + CONCAT_B + 2 * PBUF_B + W1T_B);

  auto SL = [&](int sidx) { return concat + (long)sidx * FCH * HPX; };
  const int C9 = 64 * 64 * 9, C8 = 64 * 64 * 8, C1 = 64 * 64;

  transpose_w_kernel<<<(288 * 576 + 255) / 256, 256, 0, stream>>>(w1, w1t, 288, 576);
  transpose_w_kernel<<<(64 * 288 + 255) / 256, 256, 0, stream>>>(w2, w2t, 64, 288);

  conv0_kernel<<<(2 * FCH * HPX) / 256, 256, 0, stream>>>(img, w0a, w0b, A);

  // outs[0]; base = resblock(base, cl10[0]); outs[1]; base = resblock(base, cl2[0])
  donut_b(A, first_p, SL(0), 1, stream);
  conv9(A, cl10 + 0 * C9, B, 256, 8, stream);
  conv9r(B, cl10 + 1 * C9, A, 256, 8, stream);               // base = A @256
  donut_b(A, dilres_p + 0 * C8, SL(1), 3, stream);
  conv9(A, cl2 + 0 * C9, B, 256, 8, stream);
  conv9r(B, cl2 + 1 * C9, A, 256, 8, stream);                // base = A @256

  // ---- i = 0 (dil 5 @256)
  donut_f(A, dil_p + 0 * C8, B, 256, 8, 5, stream);
  ups(B, ups_w + 0 * C1, SL(2), 256, stream);                // scale 1 (identity)
  avgpool(A, B, 7, stream);                                  // base = B @128
  conv9(B, cl10 + 2 * C9, A, 128, 7, stream);
  conv9r(A, cl10 + 3 * C9, B, 128, 7, stream);               // base = B @128
  donut_f(B, dilres_p + 1 * C8, A, 128, 7, 6, stream);
  ups(A, ups_w + 1 * C1, SL(3), 128, stream);
  conv9(B, cl2 + 2 * C9, A, 128, 7, stream);
  conv9r(A, cl2 + 3 * C9, B, 128, 7, stream);                // base = B @128

  // ---- i = 1 (dil 8 @128)
  donut_f(B, dil_p + 1 * C8, A, 128, 7, 8, stream);
  ups(A, ups_w + 1 * C1, SL(4), 128, stream);
  avgpool(B, A, 6, stream);                                  // base = A @64
  conv9(A, cl10 + 4 * C9, B, 64, 6, stream);
  conv9r(B, cl10 + 5 * C9, A, 64, 6, stream);                // base = A @64
  donut_f(A, dilres_p + 2 * C8, B, 64, 6, 8, stream);
  ups(B, ups_w + 2 * C1, SL(5), 64, stream);
  conv9(A, cl2 + 4 * C9, B, 64, 6, stream);
  conv9r(B, cl2 + 5 * C9, A, 64, 6, stream);                 // base = A @64

  // ---- i = 2 (dil 10 @64)
  donut_f(A, dil_p + 2 * C8, B, 64, 6, 10, stream);
  ups(B, ups_w + 2 * C1, SL(6), 64, stream);
  avgpool(A, B, 5, stream);                                  // base = B @32
  conv9(B, cl10 + 6 * C9, A, 32, 5, stream);
  conv9r(A, cl10 + 7 * C9, B, 32, 5, stream);                // base = B @32
  donut_f(B, dilres_p + 3 * C8, A, 32, 5, 9, stream);
  ups(A, ups_w + 3 * C1, SL(7), 32, stream);
  conv9(B, cl2 + 6 * C9, A, 32, 5, stream);
  conv9r(A, cl2 + 7 * C9, B, 32, 5, stream);                 // base = B @32

  // ---- i = 3 (dil 11 @32)
  donut_f(B, dil_p + 3 * C8, A, 32, 5, 11, stream);
  ups(A, ups_w + 3 * C1, SL(8), 32, stream);

  // ---- fused head
  head_kernel<<<dim3(1024, 2), 256, 0, stream>>>(concat, w1t, w2t, w3,
                                                 (float*)d_out);
}